// Round 1
// baseline (119.292 us; speedup 1.0000x reference)
//
#include <hip/hip_runtime.h>
#include <math.h>

#define BB 256      // batch
#define CC 1024     // channels
#define MARGIN 0.5f
#define NTILE 16    // j-tiles per row in pair kernel
#define JPT 16      // j's per tile

// ---------------------------------------------------------------------------
// Kernel A: mcsq[i,c] = m_counts[i,c]^2 (float).
// m_counts[i,c] = sum_k [ |x[i,c]-x[jk,c]| < 0.5 * mean_c |x[i]-x[jk]| ]
// where jk = first m_count indices j (ascending) with same target & sub.
// One block per row i, 256 threads, 4 c's per thread.
// ---------------------------------------------------------------------------
__global__ __launch_bounds__(256) void mcsq_kernel(
    const float* __restrict__ x, const int* __restrict__ targets,
    const int* __restrict__ subs, const int* __restrict__ m_count_p,
    float* __restrict__ mcsq)
{
    const int i = blockIdx.x;
    const int tid = threadIdx.x;
    __shared__ float red[256];
    __shared__ int idx_s[8];
    __shared__ int mcnt_s;
    if (tid == 0) {
        int mc = *m_count_p;
        if (mc > 8) mc = 8;
        const int ti = targets[i], si = subs[i];
        int cnt = 0;
        for (int j = 0; j < BB && cnt < mc; ++j) {
            if (targets[j] == ti && subs[j] == si) idx_s[cnt++] = j;
        }
        mcnt_s = cnt;
    }
    __syncthreads();
    const int mc = mcnt_s;
    const float* xi = x + (long)i * CC;
    float cnt4[4] = {0.f, 0.f, 0.f, 0.f};
    for (int k = 0; k < mc; ++k) {
        const float* xj = x + (long)idx_s[k] * CC;
        float ad[4];
        float s = 0.f;
        for (int u = 0; u < 4; ++u) {
            const int c = tid + 256 * u;
            ad[u] = fabsf(xi[c] - xj[c]);
            s += ad[u];
        }
        red[tid] = s;
        __syncthreads();
        for (int off = 128; off > 0; off >>= 1) {
            if (tid < off) red[tid] += red[tid + off];
            __syncthreads();
        }
        const float thr = red[0] * (MARGIN / CC);   // 0.5 * mean
        __syncthreads();                            // red[0] consumed before reuse
        for (int u = 0; u < 4; ++u) cnt4[u] += (ad[u] < thr) ? 1.f : 0.f;
    }
    for (int u = 0; u < 4; ++u) {
        const int c = tid + 256 * u;
        mcsq[(long)i * CC + c] = cnt4[u] * cnt4[u];
    }
}

// ---------------------------------------------------------------------------
// Kernel B: per-pair distances + partial row reductions.
// One wave handles 2 consecutive rows (i0,i1) x one tile of 16 j's.
// i-rows (x and mcsq) live in registers; each j-row is loaded once and
// serves both i's. 3 butterfly wave-reductions per (j, i).
// Grid: 128 i-pairs * 16 j-tiles = 2048 waves = 512 blocks of 4 waves.
// Outputs: pmax[i][jt] = max_j sqrt(mod_sum), pmin[i][jt] = min over
// different-identity j of sqrt(id_sum).
// ---------------------------------------------------------------------------
__global__ __launch_bounds__(256) void pair_kernel(
    const float* __restrict__ x, const float* __restrict__ mcsq,
    const int* __restrict__ targets,
    float* __restrict__ pmax, float* __restrict__ pmin)
{
    const int tid  = threadIdx.x;
    const int lane = tid & 63;
    const int gw   = blockIdx.x * 4 + (tid >> 6);  // global wave id, 0..2047
    const int p    = gw >> 4;                      // i-pair, 0..127
    const int jt   = gw & 15;                      // j-tile, 0..15
    const int i0 = 2 * p, i1 = 2 * p + 1;

    float xi0[16], xi1[16], mi0[16], mi1[16];
    #pragma unroll
    for (int t = 0; t < 16; ++t) {
        const int c = lane + 64 * t;
        xi0[t] = x[(long)i0 * CC + c];
        xi1[t] = x[(long)i1 * CC + c];
        mi0[t] = mcsq[(long)i0 * CC + c];
        mi1[t] = mcsq[(long)i1 * CC + c];
    }
    const int t0 = targets[i0], t1 = targets[i1];

    float max0 = 0.f, max1 = 0.f;
    float min0 = INFINITY, min1 = INFINITY;

    for (int jj = 0; jj < JPT; ++jj) {
        const int j = jt * JPT + jj;
        float xj[16], mj[16];
        float s0 = 0.f, s1 = 0.f;
        #pragma unroll
        for (int t = 0; t < 16; ++t) {
            const int c = lane + 64 * t;
            xj[t] = x[(long)j * CC + c];
            mj[t] = mcsq[(long)j * CC + c];
            s0 += fabsf(xi0[t] - xj[t]);
            s1 += fabsf(xi1[t] - xj[t]);
        }
        #pragma unroll
        for (int off = 32; off > 0; off >>= 1) {
            s0 += __shfl_xor(s0, off, 64);
            s1 += __shfl_xor(s1, off, 64);
        }
        const float thr0 = s0 * (MARGIN / CC);
        const float thr1 = s1 * (MARGIN / CC);
        float ids0 = 0.f, ids1 = 0.f, md0 = 0.f, md1 = 0.f;
        #pragma unroll
        for (int t = 0; t < 16; ++t) {
            const float d0 = xi0[t] - xj[t];
            const float q0 = d0 * d0;
            ids0 += (fabsf(d0) < thr0) ? q0 : 0.f;
            md0  += q0 * mi0[t] * mj[t];
            const float d1 = xi1[t] - xj[t];
            const float q1 = d1 * d1;
            ids1 += (fabsf(d1) < thr1) ? q1 : 0.f;
            md1  += q1 * mi1[t] * mj[t];
        }
        #pragma unroll
        for (int off = 32; off > 0; off >>= 1) {
            ids0 += __shfl_xor(ids0, off, 64);
            ids1 += __shfl_xor(ids1, off, 64);
            md0  += __shfl_xor(md0,  off, 64);
            md1  += __shfl_xor(md1,  off, 64);
        }
        max0 = fmaxf(max0, sqrtf(fmaxf(md0, 1e-12f)));
        max1 = fmaxf(max1, sqrtf(fmaxf(md1, 1e-12f)));
        const int tj = targets[j];
        if (tj != t0) min0 = fminf(min0, sqrtf(fmaxf(ids0, 1e-12f)));
        if (tj != t1) min1 = fminf(min1, sqrtf(fmaxf(ids1, 1e-12f)));
    }
    if (lane == 0) {
        pmax[i0 * NTILE + jt] = max0;
        pmax[i1 * NTILE + jt] = max1;
        pmin[i0 * NTILE + jt] = min0;
        pmin[i1 * NTILE + jt] = min1;
    }
}

// ---------------------------------------------------------------------------
// Kernel C: final reduce. Thread i folds its row's 16 partials, then a block
// reduction produces mean(max(10*max_mod - min_id, 0)).
// ---------------------------------------------------------------------------
__global__ __launch_bounds__(256) void final_kernel(
    const float* __restrict__ pmax, const float* __restrict__ pmin,
    float* __restrict__ out)
{
    const int i = threadIdx.x;  // row
    float mx = 0.f, mn = INFINITY;
    for (int t = 0; t < NTILE; ++t) {
        mx = fmaxf(mx, pmax[i * NTILE + t]);
        mn = fminf(mn, pmin[i * NTILE + t]);
    }
    float per = fmaxf(mx * 10.f - mn, 0.f);
    __shared__ float red[256];
    red[i] = per;
    __syncthreads();
    for (int off = 128; off > 0; off >>= 1) {
        if (i < off) red[i] += red[i + off];
        __syncthreads();
    }
    if (i == 0) out[0] = red[0] * (1.0f / BB);
}

extern "C" void kernel_launch(void* const* d_in, const int* in_sizes, int n_in,
                              void* d_out, int out_size, void* d_ws, size_t ws_size,
                              hipStream_t stream)
{
    const float* x       = (const float*)d_in[0];
    const int*   targets = (const int*)d_in[1];
    const int*   subs    = (const int*)d_in[2];
    const int*   m_count = (const int*)d_in[3];
    float* out  = (float*)d_out;

    float* mcsq = (float*)d_ws;                 // BB*CC floats = 1 MB
    float* pmax = mcsq + (long)BB * CC;         // BB*NTILE floats
    float* pmin = pmax + BB * NTILE;            // BB*NTILE floats

    mcsq_kernel <<<BB,  256, 0, stream>>>(x, targets, subs, m_count, mcsq);
    pair_kernel <<<512, 256, 0, stream>>>(x, mcsq, targets, pmax, pmin);
    final_kernel<<<1,   256, 0, stream>>>(pmax, pmin, out);
}

// Round 2
// 102.692 us; speedup vs baseline: 1.1617x; 1.1617x over previous
//
#include <hip/hip_runtime.h>
#include <math.h>

#define BB 256      // batch
#define CC 1024     // channels
#define MARGIN 0.5f
#define NTILE 32    // j-tiles per row in pair kernel
#define JPT 8       // j's per tile

// ---------------------------------------------------------------------------
// Kernel A: mcsq[i,c] = m_counts[i,c]^2 (float).
// One wave per row i. Partner selection (first m_count j's, ascending, with
// same target & sub; padded with smallest non-matching j's per argsort-stable
// semantics) via ballot — no serial scan, no __syncthreads.
// ---------------------------------------------------------------------------
__global__ __launch_bounds__(64) void mcsq_kernel(
    const float* __restrict__ x, const int* __restrict__ targets,
    const int* __restrict__ subs, const int* __restrict__ m_count_p,
    float* __restrict__ mcsq)
{
    const int i = blockIdx.x;
    const int lane = threadIdx.x;
    const int ti = targets[i], si = subs[i];
    int mc = *m_count_p;
    if (mc > 8) mc = 8;

    unsigned long long masks[4];
    #pragma unroll
    for (int q = 0; q < 4; ++q) {
        const int j = q * 64 + lane;
        masks[q] = __ballot(targets[j] == ti && subs[j] == si);
    }
    int idx[8];
    int cnt = 0;
    for (int q = 0; q < 4 && cnt < mc; ++q) {
        unsigned long long m = masks[q];
        while (m && cnt < mc) {
            const int b = __ffsll(m) - 1;
            idx[cnt++] = q * 64 + b;
            m &= m - 1;
        }
    }
    for (int q = 0; q < 4 && cnt < mc; ++q) {   // stable-argsort padding
        unsigned long long m = ~masks[q];
        while (m && cnt < mc) {
            const int b = __ffsll(m) - 1;
            idx[cnt++] = q * 64 + b;
            m &= m - 1;
        }
    }

    const float* xi = x + (long)i * CC;
    float ad[16], cnt16[16];
    #pragma unroll
    for (int t = 0; t < 16; ++t) cnt16[t] = 0.f;

    for (int k = 0; k < cnt; ++k) {
        const float* xj = x + (long)idx[k] * CC;
        float s = 0.f;
        #pragma unroll
        for (int t = 0; t < 16; ++t) {
            const int c = lane + 64 * t;
            ad[t] = fabsf(xi[c] - xj[c]);
            s += ad[t];
        }
        #pragma unroll
        for (int off = 32; off > 0; off >>= 1) s += __shfl_xor(s, off, 64);
        const float thr = s * (MARGIN / CC);   // 0.5 * mean
        #pragma unroll
        for (int t = 0; t < 16; ++t) cnt16[t] += (ad[t] < thr) ? 1.f : 0.f;
    }
    #pragma unroll
    for (int t = 0; t < 16; ++t) {
        const int c = lane + 64 * t;
        mcsq[(long)i * CC + c] = cnt16[t] * cnt16[t];
    }
}

// ---------------------------------------------------------------------------
// Kernel B: per-pair distances + partial row reductions.
// One wave = 2 consecutive i-rows x one tile of 8 j's, j-loop unrolled by 2
// so 4 pass-1 and 8 pass-2 butterfly reductions are in flight at once.
// Grid: 128 i-pairs * 32 j-tiles = 4096 waves = 1024 blocks of 4 waves.
// ---------------------------------------------------------------------------
__global__ __launch_bounds__(256) void pair_kernel(
    const float* __restrict__ x, const float* __restrict__ mcsq,
    const int* __restrict__ targets,
    float* __restrict__ pmax, float* __restrict__ pmin)
{
    const int tid  = threadIdx.x;
    const int lane = tid & 63;
    const int gw   = blockIdx.x * 4 + (tid >> 6);  // 0..4095
    const int p    = gw >> 5;                      // i-pair, 0..127
    const int jt   = gw & 31;                      // j-tile, 0..31
    const int i0 = 2 * p, i1 = 2 * p + 1;

    float xi0[16], xi1[16], mi0[16], mi1[16];
    #pragma unroll
    for (int t = 0; t < 16; ++t) {
        const int c = lane + 64 * t;
        xi0[t] = x[(long)i0 * CC + c];
        xi1[t] = x[(long)i1 * CC + c];
        mi0[t] = mcsq[(long)i0 * CC + c];
        mi1[t] = mcsq[(long)i1 * CC + c];
    }
    const int t0 = targets[i0], t1 = targets[i1];

    float max0 = 0.f, max1 = 0.f;
    float min0 = INFINITY, min1 = INFINITY;

    for (int jj = 0; jj < JPT; jj += 2) {
        const int ja = jt * JPT + jj;
        const int jb = ja + 1;
        float xa[16], ma[16], xb[16], mb[16];
        float sa0 = 0.f, sa1 = 0.f, sb0 = 0.f, sb1 = 0.f;
        #pragma unroll
        for (int t = 0; t < 16; ++t) {
            const int c = lane + 64 * t;
            xa[t] = x[(long)ja * CC + c];
            ma[t] = mcsq[(long)ja * CC + c];
            xb[t] = x[(long)jb * CC + c];
            mb[t] = mcsq[(long)jb * CC + c];
            sa0 += fabsf(xi0[t] - xa[t]);
            sa1 += fabsf(xi1[t] - xa[t]);
            sb0 += fabsf(xi0[t] - xb[t]);
            sb1 += fabsf(xi1[t] - xb[t]);
        }
        #pragma unroll
        for (int off = 32; off > 0; off >>= 1) {
            sa0 += __shfl_xor(sa0, off, 64);
            sa1 += __shfl_xor(sa1, off, 64);
            sb0 += __shfl_xor(sb0, off, 64);
            sb1 += __shfl_xor(sb1, off, 64);
        }
        const float ta0 = sa0 * (MARGIN / CC);
        const float ta1 = sa1 * (MARGIN / CC);
        const float tb0 = sb0 * (MARGIN / CC);
        const float tb1 = sb1 * (MARGIN / CC);

        float ia0 = 0.f, ia1 = 0.f, ib0 = 0.f, ib1 = 0.f;
        float da0 = 0.f, da1 = 0.f, db0 = 0.f, db1 = 0.f;
        #pragma unroll
        for (int t = 0; t < 16; ++t) {
            const float d0a = xi0[t] - xa[t];
            const float q0a = d0a * d0a;
            ia0 += (fabsf(d0a) < ta0) ? q0a : 0.f;
            da0 += q0a * mi0[t] * ma[t];
            const float d1a = xi1[t] - xa[t];
            const float q1a = d1a * d1a;
            ia1 += (fabsf(d1a) < ta1) ? q1a : 0.f;
            da1 += q1a * mi1[t] * ma[t];
            const float d0b = xi0[t] - xb[t];
            const float q0b = d0b * d0b;
            ib0 += (fabsf(d0b) < tb0) ? q0b : 0.f;
            db0 += q0b * mi0[t] * mb[t];
            const float d1b = xi1[t] - xb[t];
            const float q1b = d1b * d1b;
            ib1 += (fabsf(d1b) < tb1) ? q1b : 0.f;
            db1 += q1b * mi1[t] * mb[t];
        }
        #pragma unroll
        for (int off = 32; off > 0; off >>= 1) {
            ia0 += __shfl_xor(ia0, off, 64);
            ia1 += __shfl_xor(ia1, off, 64);
            ib0 += __shfl_xor(ib0, off, 64);
            ib1 += __shfl_xor(ib1, off, 64);
            da0 += __shfl_xor(da0, off, 64);
            da1 += __shfl_xor(da1, off, 64);
            db0 += __shfl_xor(db0, off, 64);
            db1 += __shfl_xor(db1, off, 64);
        }
        max0 = fmaxf(max0, sqrtf(fmaxf(da0, 1e-12f)));
        max1 = fmaxf(max1, sqrtf(fmaxf(da1, 1e-12f)));
        max0 = fmaxf(max0, sqrtf(fmaxf(db0, 1e-12f)));
        max1 = fmaxf(max1, sqrtf(fmaxf(db1, 1e-12f)));
        const int tja = targets[ja], tjb = targets[jb];
        if (tja != t0) min0 = fminf(min0, sqrtf(fmaxf(ia0, 1e-12f)));
        if (tja != t1) min1 = fminf(min1, sqrtf(fmaxf(ia1, 1e-12f)));
        if (tjb != t0) min0 = fminf(min0, sqrtf(fmaxf(ib0, 1e-12f)));
        if (tjb != t1) min1 = fminf(min1, sqrtf(fmaxf(ib1, 1e-12f)));
    }
    if (lane == 0) {
        pmax[i0 * NTILE + jt] = max0;
        pmax[i1 * NTILE + jt] = max1;
        pmin[i0 * NTILE + jt] = min0;
        pmin[i1 * NTILE + jt] = min1;
    }
}

// ---------------------------------------------------------------------------
// Kernel C: final reduce over j-tiles, then block sum -> mean.
// ---------------------------------------------------------------------------
__global__ __launch_bounds__(256) void final_kernel(
    const float* __restrict__ pmax, const float* __restrict__ pmin,
    float* __restrict__ out)
{
    const int i = threadIdx.x;  // row
    float mx = 0.f, mn = INFINITY;
    for (int t = 0; t < NTILE; ++t) {
        mx = fmaxf(mx, pmax[i * NTILE + t]);
        mn = fminf(mn, pmin[i * NTILE + t]);
    }
    float per = fmaxf(mx * 10.f - mn, 0.f);
    __shared__ float red[256];
    red[i] = per;
    __syncthreads();
    for (int off = 128; off > 0; off >>= 1) {
        if (i < off) red[i] += red[i + off];
        __syncthreads();
    }
    if (i == 0) out[0] = red[0] * (1.0f / BB);
}

extern "C" void kernel_launch(void* const* d_in, const int* in_sizes, int n_in,
                              void* d_out, int out_size, void* d_ws, size_t ws_size,
                              hipStream_t stream)
{
    const float* x       = (const float*)d_in[0];
    const int*   targets = (const int*)d_in[1];
    const int*   subs    = (const int*)d_in[2];
    const int*   m_count = (const int*)d_in[3];
    float* out  = (float*)d_out;

    float* mcsq = (float*)d_ws;                 // BB*CC floats = 1 MB
    float* pmax = mcsq + (long)BB * CC;         // BB*NTILE floats
    float* pmin = pmax + BB * NTILE;            // BB*NTILE floats

    mcsq_kernel <<<BB,   64, 0, stream>>>(x, targets, subs, m_count, mcsq);
    pair_kernel <<<1024, 256, 0, stream>>>(x, mcsq, targets, pmax, pmin);
    final_kernel<<<1,   256, 0, stream>>>(pmax, pmin, out);
}

// Round 3
// 96.417 us; speedup vs baseline: 1.2372x; 1.0651x over previous
//
#include <hip/hip_runtime.h>
#include <math.h>

#define BB 256      // batch
#define CC 1024     // channels
#define CC4 (CC/4)  // row length in float4
#define MARGIN 0.5f
#define NTILE 32    // j-tiles per row in pair kernel
#define JPT 8       // j's per tile

// ---------------------------------------------------------------------------
// Kernel A: mcsq[i,c] = m_counts[i,c]^2 (float).
// One wave per row i. Partner selection via ballot; float4 loads.
// ---------------------------------------------------------------------------
__global__ __launch_bounds__(64) void mcsq_kernel(
    const float* __restrict__ x, const int* __restrict__ targets,
    const int* __restrict__ subs, const int* __restrict__ m_count_p,
    float* __restrict__ mcsq)
{
    const int i = blockIdx.x;
    const int lane = threadIdx.x;
    const int ti = targets[i], si = subs[i];
    int mc = *m_count_p;
    if (mc > 8) mc = 8;

    unsigned long long masks[4];
    #pragma unroll
    for (int q = 0; q < 4; ++q) {
        const int j = q * 64 + lane;
        masks[q] = __ballot(targets[j] == ti && subs[j] == si);
    }
    int idx[8];
    int cnt = 0;
    for (int q = 0; q < 4 && cnt < mc; ++q) {
        unsigned long long m = masks[q];
        while (m && cnt < mc) {
            const int b = __ffsll(m) - 1;
            idx[cnt++] = q * 64 + b;
            m &= m - 1;
        }
    }
    for (int q = 0; q < 4 && cnt < mc; ++q) {   // stable-argsort padding
        unsigned long long m = ~masks[q];
        while (m && cnt < mc) {
            const int b = __ffsll(m) - 1;
            idx[cnt++] = q * 64 + b;
            m &= m - 1;
        }
    }

    const float4* x4 = (const float4*)x;
    float4 xi[4];
    #pragma unroll
    for (int t = 0; t < 4; ++t) xi[t] = x4[(long)i * CC4 + lane + 64 * t];

    float4 c4[4];
    #pragma unroll
    for (int t = 0; t < 4; ++t) c4[t] = make_float4(0.f, 0.f, 0.f, 0.f);

    for (int k = 0; k < cnt; ++k) {
        float4 ad[4];
        float s = 0.f;
        #pragma unroll
        for (int t = 0; t < 4; ++t) {
            const float4 xj = x4[(long)idx[k] * CC4 + lane + 64 * t];
            ad[t].x = fabsf(xi[t].x - xj.x);
            ad[t].y = fabsf(xi[t].y - xj.y);
            ad[t].z = fabsf(xi[t].z - xj.z);
            ad[t].w = fabsf(xi[t].w - xj.w);
            s += ad[t].x + ad[t].y + ad[t].z + ad[t].w;
        }
        #pragma unroll
        for (int off = 32; off > 0; off >>= 1) s += __shfl_xor(s, off, 64);
        const float thr = s * (MARGIN / CC);   // 0.5 * mean
        #pragma unroll
        for (int t = 0; t < 4; ++t) {
            c4[t].x += (ad[t].x < thr) ? 1.f : 0.f;
            c4[t].y += (ad[t].y < thr) ? 1.f : 0.f;
            c4[t].z += (ad[t].z < thr) ? 1.f : 0.f;
            c4[t].w += (ad[t].w < thr) ? 1.f : 0.f;
        }
    }
    float4* m4 = (float4*)mcsq;
    #pragma unroll
    for (int t = 0; t < 4; ++t) {
        float4 o;
        o.x = c4[t].x * c4[t].x;
        o.y = c4[t].y * c4[t].y;
        o.z = c4[t].z * c4[t].z;
        o.w = c4[t].w * c4[t].w;
        m4[(long)i * CC4 + lane + 64 * t] = o;
    }
}

// ---------------------------------------------------------------------------
// Kernel B: per-pair distances + partial row reductions.
// One wave = 2 consecutive i-rows x one tile of 8 j's. All global access as
// float4 (dwordx4) to cut VMEM instruction count and address VALU 4x.
// Grid: 128 i-pairs * 32 j-tiles = 4096 waves = 1024 blocks of 4 waves.
// ---------------------------------------------------------------------------
__global__ __launch_bounds__(256) void pair_kernel(
    const float* __restrict__ x, const float* __restrict__ mcsq,
    const int* __restrict__ targets,
    float* __restrict__ pmax, float* __restrict__ pmin)
{
    const int tid  = threadIdx.x;
    const int lane = tid & 63;
    const int gw   = blockIdx.x * 4 + (tid >> 6);  // 0..4095
    const int p    = gw >> 5;                      // i-pair, 0..127
    const int jt   = gw & 31;                      // j-tile, 0..31
    const int i0 = 2 * p, i1 = 2 * p + 1;

    const float4* x4 = (const float4*)x;
    const float4* m4 = (const float4*)mcsq;

    float4 xi0[4], xi1[4], mi0[4], mi1[4];
    #pragma unroll
    for (int t = 0; t < 4; ++t) {
        const int c4 = lane + 64 * t;
        xi0[t] = x4[(long)i0 * CC4 + c4];
        xi1[t] = x4[(long)i1 * CC4 + c4];
        mi0[t] = m4[(long)i0 * CC4 + c4];
        mi1[t] = m4[(long)i1 * CC4 + c4];
    }
    const int t0 = targets[i0], t1 = targets[i1];

    float max0 = 0.f, max1 = 0.f;
    float min0 = INFINITY, min1 = INFINITY;

    for (int jj = 0; jj < JPT; ++jj) {
        const int j = jt * JPT + jj;
        float4 xa[4], ma[4];
        float s0 = 0.f, s1 = 0.f;
        #pragma unroll
        for (int t = 0; t < 4; ++t) {
            const int c4 = lane + 64 * t;
            xa[t] = x4[(long)j * CC4 + c4];
            ma[t] = m4[(long)j * CC4 + c4];
            s0 += fabsf(xi0[t].x - xa[t].x) + fabsf(xi0[t].y - xa[t].y)
                + fabsf(xi0[t].z - xa[t].z) + fabsf(xi0[t].w - xa[t].w);
            s1 += fabsf(xi1[t].x - xa[t].x) + fabsf(xi1[t].y - xa[t].y)
                + fabsf(xi1[t].z - xa[t].z) + fabsf(xi1[t].w - xa[t].w);
        }
        #pragma unroll
        for (int off = 32; off > 0; off >>= 1) {
            s0 += __shfl_xor(s0, off, 64);
            s1 += __shfl_xor(s1, off, 64);
        }
        const float thr0 = s0 * (MARGIN / CC);
        const float thr1 = s1 * (MARGIN / CC);

        float ids0 = 0.f, ids1 = 0.f, md0 = 0.f, md1 = 0.f;
        #pragma unroll
        for (int t = 0; t < 4; ++t) {
            #pragma unroll
            for (int u = 0; u < 4; ++u) {
                const float xav = (&xa[t].x)[u];
                const float mav = (&ma[t].x)[u];
                const float d0 = (&xi0[t].x)[u] - xav;
                const float q0 = d0 * d0;
                ids0 += (fabsf(d0) < thr0) ? q0 : 0.f;
                md0  += q0 * (&mi0[t].x)[u] * mav;
                const float d1 = (&xi1[t].x)[u] - xav;
                const float q1 = d1 * d1;
                ids1 += (fabsf(d1) < thr1) ? q1 : 0.f;
                md1  += q1 * (&mi1[t].x)[u] * mav;
            }
        }
        #pragma unroll
        for (int off = 32; off > 0; off >>= 1) {
            ids0 += __shfl_xor(ids0, off, 64);
            ids1 += __shfl_xor(ids1, off, 64);
            md0  += __shfl_xor(md0,  off, 64);
            md1  += __shfl_xor(md1,  off, 64);
        }
        max0 = fmaxf(max0, sqrtf(fmaxf(md0, 1e-12f)));
        max1 = fmaxf(max1, sqrtf(fmaxf(md1, 1e-12f)));
        const int tj = targets[j];
        if (tj != t0) min0 = fminf(min0, sqrtf(fmaxf(ids0, 1e-12f)));
        if (tj != t1) min1 = fminf(min1, sqrtf(fmaxf(ids1, 1e-12f)));
    }
    if (lane == 0) {
        pmax[i0 * NTILE + jt] = max0;
        pmax[i1 * NTILE + jt] = max1;
        pmin[i0 * NTILE + jt] = min0;
        pmin[i1 * NTILE + jt] = min1;
    }
}

// ---------------------------------------------------------------------------
// Kernel C: final reduce over j-tiles, then block sum -> mean.
// ---------------------------------------------------------------------------
__global__ __launch_bounds__(256) void final_kernel(
    const float* __restrict__ pmax, const float* __restrict__ pmin,
    float* __restrict__ out)
{
    const int i = threadIdx.x;  // row
    float mx = 0.f, mn = INFINITY;
    for (int t = 0; t < NTILE; ++t) {
        mx = fmaxf(mx, pmax[i * NTILE + t]);
        mn = fminf(mn, pmin[i * NTILE + t]);
    }
    float per = fmaxf(mx * 10.f - mn, 0.f);
    __shared__ float red[256];
    red[i] = per;
    __syncthreads();
    for (int off = 128; off > 0; off >>= 1) {
        if (i < off) red[i] += red[i + off];
        __syncthreads();
    }
    if (i == 0) out[0] = red[0] * (1.0f / BB);
}

extern "C" void kernel_launch(void* const* d_in, const int* in_sizes, int n_in,
                              void* d_out, int out_size, void* d_ws, size_t ws_size,
                              hipStream_t stream)
{
    const float* x       = (const float*)d_in[0];
    const int*   targets = (const int*)d_in[1];
    const int*   subs    = (const int*)d_in[2];
    const int*   m_count = (const int*)d_in[3];
    float* out  = (float*)d_out;

    float* mcsq = (float*)d_ws;                 // BB*CC floats = 1 MB
    float* pmax = mcsq + (long)BB * CC;         // BB*NTILE floats
    float* pmin = pmax + BB * NTILE;            // BB*NTILE floats

    mcsq_kernel <<<BB,   64, 0, stream>>>(x, targets, subs, m_count, mcsq);
    pair_kernel <<<1024, 256, 0, stream>>>(x, mcsq, targets, pmax, pmin);
    final_kernel<<<1,   256, 0, stream>>>(pmax, pmin, out);
}